// Round 10
// baseline (241.720 us; speedup 1.0000x reference)
//
#include <hip/hip_runtime.h>
#include <hip/hip_bf16.h>

#define TT 512
#define BPB 4                 // batches per block
#define NBLK (2048 / BPB)     // 512 blocks = 2 per CU
#define OUTD 64

typedef __attribute__((ext_vector_type(8))) short short8;
typedef __attribute__((ext_vector_type(4))) float f32x4;

__device__ __forceinline__ short f2bf(float x) {  // RNE float->bf16 (staging only)
    union { float f; unsigned u; } v; v.f = x;
    unsigned r = (v.u + 0x7FFFu + ((v.u >> 16) & 1u)) >> 16;
    return (short)r;
}
__device__ __forceinline__ short cvt_bf16(float x) {  // 1-instr RNE cvt
    unsigned r;
    asm("v_cvt_pk_bf16_f32 %0, %1, %1" : "=v"(r) : "v"(x));
    return (short)r;
}
__device__ __forceinline__ float sigm(float x) {
    return __builtin_amdgcn_rcpf(1.f + __expf(-x));
}
__device__ __forceinline__ float tanh_fast(float x) {
    return 2.f * sigm(2.f * x) - 1.f;
}

// In-lane LSTM cell update: mg regs = {i,f,g,o} for this lane's (unit,batch)
#define ACT_UPDATE(acc, c, hval)                                   \
    {                                                              \
        float gi = sigm((acc)[0]);                                 \
        float gf = sigm((acc)[1]);                                 \
        float gg = tanh_fast((acc)[2]);                            \
        float go = sigm((acc)[3]);                                 \
        (c) = gf * (c) + gi * gg;                                  \
        (hval) = go * tanh_fast((c));                              \
    }

// FOLD4: tiles t'=0..3 have valid batch cols 0..3 only. Route tile (c>>2),
// col (c&3) data to lane col c via 2-stage butterfly (12 shfl_xor).
// Stage1 (xor4): lanes 0..7 get tiles {0,1}, also build tiles {2,3} pair.
// Stage2 (xor8): lanes 8..15 pull the {2,3} pair from lanes 0..7.
#define FOLD4(mg, a0, a1, a2, a3, c4, c8)                          \
    {                                                              \
        _Pragma("unroll")                                          \
        for (int r = 0; r < 4; ++r) {                              \
            float s1 = __shfl_xor((a1)[r], 4);                     \
            float m1 = (c4) ? s1 : (a0)[r];                        \
            float s2 = __shfl_xor((a3)[r], 4);                     \
            float m2 = (c4) ? s2 : (a2)[r];                        \
            float s3 = __shfl_xor(m2, 8);                          \
            (mg)[r] = (c8) ? s3 : m1;                              \
        }                                                          \
    }

__global__ __launch_bounds__(256, 2) void lstm2_fold4_kernel(
    const float* __restrict__ imu,
    const float* __restrict__ w_ih0, const float* __restrict__ w_hh0,
    const float* __restrict__ b_ih0, const float* __restrict__ b_hh0,
    const float* __restrict__ w_ih1, const float* __restrict__ w_hh1,
    const float* __restrict__ b_ih1, const float* __restrict__ b_hh1,
    const float* __restrict__ wf, const float* __restrict__ bf,
    const float* __restrict__ wn, const float* __restrict__ bn,
    float* __restrict__ out)
{
    const int tid   = threadIdx.x;
    const int l     = tid & 63;
    const int w     = tid >> 6;          // 4 waves
    const int layer = w >> 1;            // 0: LSTM1, 1: LSTM2
    const int p     = w & 1;             // which half of the 8 tiles (tiles 4p+t')
    const int c     = l & 15;            // B col; A row m; D col
    const int q     = l >> 4;            // k-group / D row-quad
    const int b     = c & 3;             // valid batch (all lanes valid after fold)
    const int tsel  = c >> 2;            // tile this lane owns after fold
    const bool c4   = (c & 4) != 0;
    const bool c8   = (c & 8) != 0;
    const int unit  = 16 * p + 4 * tsel + q;   // owned unit after fold

    __shared__ __align__(16) short xfrag[TT + 4][BPB][8];  // [t][batch][k] bf16; +4 pad
    __shared__ __align__(16) short h1f[2][16][40];         // [parity][batchrow][unit]; rows 4-15 stay 0
    __shared__ __align__(16) short h2f[2][16][40];
    __shared__ __align__(16) float lasth[BPB][36];         // [batch][unit] fp32

    // ---- zero h buffers and xfrag pad rows
    {
        short* p1 = &h1f[0][0][0];
        short* p2 = &h2f[0][0][0];
        for (int i = tid; i < 2 * 16 * 40; i += 256) { p1[i] = 0; p2[i] = 0; }
        short* px = &xfrag[TT][0][0];
        for (int i = tid; i < 4 * BPB * 8; i += 256) px[i] = 0;
    }

    // ---- stage x into [t][batch][k] bf16
    {
        const int bg0 = blockIdx.x * BPB;
        for (int pp = tid; pp < BPB * TT; pp += 256) {
            const int bb = pp >> 9;          // 0..3
            const int t  = pp & (TT - 1);
            const float* src = imu + ((size_t)(bg0 + bb) * TT + t) * 6;
            float2 a0 = *(const float2*)(src);
            float2 a1 = *(const float2*)(src + 2);
            float2 a2 = *(const float2*)(src + 4);
            unsigned* dst = (unsigned*)&xfrag[t][bb][0];
            dst[0] = (unsigned short)f2bf(a0.x) | ((unsigned)(unsigned short)f2bf(a0.y) << 16);
            dst[1] = (unsigned short)f2bf(a1.x) | ((unsigned)(unsigned short)f2bf(a1.y) << 16);
            dst[2] = (unsigned short)f2bf(a2.x) | ((unsigned)(unsigned short)f2bf(a2.y) << 16);
            dst[3] = 0u;
        }
    }

    // ---- A-fragments: wave owns tiles tau = 4p+t', t'=0..3.
    // frag row m=c -> gate G = (m&3)*32 + tau*4 + (m>>2); D reg r = gate type r.
    short8 AF[4], AS[4];      // first operand (x / h1-in), second (h1-rec / h2-rec)
    f32x4 bias[4];
    #pragma unroll
    for (int tp = 0; tp < 4; ++tp) {
        const int tau = 4 * p + tp;
        const int G   = (c & 3) * 32 + tau * 4 + (c >> 2);
        const int u   = 16 * p + 4 * tp + q;
        if (layer == 0) {
            #pragma unroll
            for (int j = 0; j < 8; ++j) {
                AF[tp][j] = (q == 0 && j < 6) ? f2bf(w_ih0[G * 6 + j]) : (short)0;
                AS[tp][j] = f2bf(w_hh0[G * 32 + q * 8 + j]);
            }
            #pragma unroll
            for (int r = 0; r < 4; ++r)
                bias[tp][r] = b_ih0[r * 32 + u] + b_hh0[r * 32 + u];
        } else {
            #pragma unroll
            for (int j = 0; j < 8; ++j) {
                AF[tp][j] = f2bf(w_ih1[G * 32 + q * 8 + j]);
                AS[tp][j] = f2bf(w_hh1[G * 32 + q * 8 + j]);
            }
            #pragma unroll
            for (int r = 0; r < 4; ++r)
                bias[tp][r] = b_ih1[r * 32 + u] + b_hh1[r * 32 + u];
        }
    }

    float cst = 0.f;                     // this lane's single cell state

    const short8* h1r0 = (const short8*)&h1f[0][c][q * 8];
    const short8* h1r1 = (const short8*)&h1f[1][c][q * 8];
    const short8* h2r0 = (const short8*)&h2f[0][c][q * 8];
    const short8* h2r1 = (const short8*)&h2f[1][c][q * 8];

    __syncthreads();

    // ======== prologue: L1 gates(0) with h1=0; prime xacc = x(1)-partial ========
    short8 xvE = (short8)0, xvO = (short8)0;
    f32x4 xacc[4];
    #pragma unroll
    for (int tp = 0; tp < 4; ++tp) xacc[tp] = bias[tp];
    if (layer == 0) {
        short8 xv = *(const short8*)&xfrag[0][b][0];
        f32x4 a0 = __builtin_amdgcn_mfma_f32_16x16x32_bf16(AF[0], xv, bias[0], 0, 0, 0);
        f32x4 a1 = __builtin_amdgcn_mfma_f32_16x16x32_bf16(AF[1], xv, bias[1], 0, 0, 0);
        f32x4 a2 = __builtin_amdgcn_mfma_f32_16x16x32_bf16(AF[2], xv, bias[2], 0, 0, 0);
        f32x4 a3 = __builtin_amdgcn_mfma_f32_16x16x32_bf16(AF[3], xv, bias[3], 0, 0, 0);
        f32x4 mg;
        FOLD4(mg, a0, a1, a2, a3, c4, c8);
        float h;
        ACT_UPDATE(mg, cst, h);
        h1f[1][b][unit] = cvt_bf16(h);
        short8 xv1 = *(const short8*)&xfrag[1][b][0];
        #pragma unroll
        for (int tp = 0; tp < 4; ++tp)
            xacc[tp] = __builtin_amdgcn_mfma_f32_16x16x32_bf16(AF[tp], xv1, bias[tp], 0, 0, 0);
        xvE = *(const short8*)&xfrag[2][b][0];
    }
    __syncthreads();

    // ======== main loop: STEP(T) = L1 gates(T+1) || L2 gates(T) ========
#define STEP(T, H1R, H2R, WP, XVC, XVL)                                         \
    {                                                                           \
        if (layer == 0) {                                                       \
            short8 hv = *(H1R);                                                 \
            f32x4 a0 = __builtin_amdgcn_mfma_f32_16x16x32_bf16(AS[0], hv, xacc[0], 0, 0, 0); \
            f32x4 a1 = __builtin_amdgcn_mfma_f32_16x16x32_bf16(AS[1], hv, xacc[1], 0, 0, 0); \
            f32x4 a2 = __builtin_amdgcn_mfma_f32_16x16x32_bf16(AS[2], hv, xacc[2], 0, 0, 0); \
            f32x4 a3 = __builtin_amdgcn_mfma_f32_16x16x32_bf16(AS[3], hv, xacc[3], 0, 0, 0); \
            f32x4 mg;                                                           \
            FOLD4(mg, a0, a1, a2, a3, c4, c8);                                  \
            float h;                                                            \
            ACT_UPDATE(mg, cst, h);                                             \
            h1f[WP][b][unit] = cvt_bf16(h);                                     \
            _Pragma("unroll")                                                   \
            for (int tp = 0; tp < 4; ++tp)                                      \
                xacc[tp] = __builtin_amdgcn_mfma_f32_16x16x32_bf16(AF[tp], XVC, bias[tp], 0, 0, 0); \
            XVL = *(const short8*)&xfrag[(T) + 3][b][0];                        \
        } else {                                                                \
            short8 av = *(H1R);                                                 \
            short8 bv = *(H2R);                                                 \
            f32x4 a0 = __builtin_amdgcn_mfma_f32_16x16x32_bf16(AF[0], av, bias[0], 0, 0, 0); \
            f32x4 a1 = __builtin_amdgcn_mfma_f32_16x16x32_bf16(AF[1], av, bias[1], 0, 0, 0); \
            f32x4 a2 = __builtin_amdgcn_mfma_f32_16x16x32_bf16(AF[2], av, bias[2], 0, 0, 0); \
            f32x4 a3 = __builtin_amdgcn_mfma_f32_16x16x32_bf16(AF[3], av, bias[3], 0, 0, 0); \
            a0 = __builtin_amdgcn_mfma_f32_16x16x32_bf16(AS[0], bv, a0, 0, 0, 0); \
            a1 = __builtin_amdgcn_mfma_f32_16x16x32_bf16(AS[1], bv, a1, 0, 0, 0); \
            a2 = __builtin_amdgcn_mfma_f32_16x16x32_bf16(AS[2], bv, a2, 0, 0, 0); \
            a3 = __builtin_amdgcn_mfma_f32_16x16x32_bf16(AS[3], bv, a3, 0, 0, 0); \
            f32x4 mg;                                                           \
            FOLD4(mg, a0, a1, a2, a3, c4, c8);                                  \
            float h;                                                            \
            ACT_UPDATE(mg, cst, h);                                             \
            h2f[WP][b][unit] = cvt_bf16(h);                                     \
        }                                                                       \
        __syncthreads();                                                        \
    }

    #pragma unroll 1
    for (int t = 0; t < TT - 2; t += 2) {
        STEP(t,     h1r1, h2r1, 0, xvE, xvO)   // even T: read parity 1, write 0
        STEP(t + 1, h1r0, h2r0, 1, xvO, xvE)   // odd  T: read parity 0, write 1
    }
    STEP(TT - 2, h1r1, h2r1, 0, xvE, xvO)      // T=510 (prefetch touches pad row)

    // ======== epilogue: L2 gates(511) -> lasth (fp32) ========
    if (layer == 1) {
        short8 av = *h1r0;           // h1(511) at parity 0
        short8 bv = *h2r0;           // h2(510) at parity 0
        f32x4 a0 = __builtin_amdgcn_mfma_f32_16x16x32_bf16(AF[0], av, bias[0], 0, 0, 0);
        f32x4 a1 = __builtin_amdgcn_mfma_f32_16x16x32_bf16(AF[1], av, bias[1], 0, 0, 0);
        f32x4 a2 = __builtin_amdgcn_mfma_f32_16x16x32_bf16(AF[2], av, bias[2], 0, 0, 0);
        f32x4 a3 = __builtin_amdgcn_mfma_f32_16x16x32_bf16(AF[3], av, bias[3], 0, 0, 0);
        a0 = __builtin_amdgcn_mfma_f32_16x16x32_bf16(AS[0], bv, a0, 0, 0, 0);
        a1 = __builtin_amdgcn_mfma_f32_16x16x32_bf16(AS[1], bv, a1, 0, 0, 0);
        a2 = __builtin_amdgcn_mfma_f32_16x16x32_bf16(AS[2], bv, a2, 0, 0, 0);
        a3 = __builtin_amdgcn_mfma_f32_16x16x32_bf16(AS[3], bv, a3, 0, 0, 0);
        f32x4 mg;
        FOLD4(mg, a0, a1, a2, a3, c4, c8);
        float h;
        ACT_UPDATE(mg, cst, h);
        lasth[b][unit] = h;
    }
    __syncthreads();

    // ======== heads: 256 threads = 4 batches x 64 outputs ========
    {
        const int bb = tid >> 6;           // 0..3 (wave-uniform)
        const int o  = tid & 63;
        float accF = bf[o], accN = bn[o];
        const float4* wf4 = (const float4*)(wf + o * 32);
        const float4* wn4 = (const float4*)(wn + o * 32);
        const float4* hv4 = (const float4*)&lasth[bb][0];
        #pragma unroll
        for (int k = 0; k < 8; ++k) {
            float4 h4 = hv4[k];
            float4 f4 = wf4[k];
            float4 n4 = wn4[k];
            accF += f4.x * h4.x + f4.y * h4.y + f4.z * h4.z + f4.w * h4.w;
            accN += n4.x * h4.x + n4.y * h4.y + n4.z * h4.z + n4.w * h4.w;
        }
        const size_t bg = (size_t)blockIdx.x * BPB + bb;
        out[bg * OUTD + o] = accF;
        out[(size_t)2048 * OUTD + bg * OUTD + o] = __expf(accN);
    }
}

extern "C" void kernel_launch(void* const* d_in, const int* in_sizes, int n_in,
                              void* d_out, int out_size, void* d_ws, size_t ws_size,
                              hipStream_t stream) {
    const float* imu   = (const float*)d_in[0];
    const float* w_ih0 = (const float*)d_in[1];
    const float* w_hh0 = (const float*)d_in[2];
    const float* b_ih0 = (const float*)d_in[3];
    const float* b_hh0 = (const float*)d_in[4];
    const float* w_ih1 = (const float*)d_in[5];
    const float* w_hh1 = (const float*)d_in[6];
    const float* b_ih1 = (const float*)d_in[7];
    const float* b_hh1 = (const float*)d_in[8];
    const float* wf    = (const float*)d_in[9];
    const float* bf    = (const float*)d_in[10];
    const float* wn    = (const float*)d_in[11];
    const float* bn    = (const float*)d_in[12];
    float* out = (float*)d_out;

    lstm2_fold4_kernel<<<dim3(NBLK), dim3(256), 0, stream>>>(
        imu, w_ih0, w_hh0, b_ih0, b_hh0,
        w_ih1, w_hh1, b_ih1, b_hh1,
        wf, bf, wn, bn, out);
}

// Round 11
// 209.592 us; speedup vs baseline: 1.1533x; 1.1533x over previous
//
#include <hip/hip_runtime.h>
#include <hip/hip_bf16.h>

#define TT 512
#define BPB 16                // batches per block (= dense MFMA tile width)
#define NBLK (2048 / BPB)     // 128 blocks
#define OUTD 64

typedef __attribute__((ext_vector_type(8))) short short8;
typedef __attribute__((ext_vector_type(4))) float f32x4;

__device__ __forceinline__ short f2bf(float x) {  // RNE float->bf16 (staging only)
    union { float f; unsigned u; } v; v.f = x;
    unsigned r = (v.u + 0x7FFFu + ((v.u >> 16) & 1u)) >> 16;
    return (short)r;
}
__device__ __forceinline__ short cvt_bf16(float x) {  // 1-instr RNE cvt
    unsigned r;
    asm("v_cvt_pk_bf16_f32 %0, %1, %1" : "=v"(r) : "v"(x));
    return (short)r;
}
__device__ __forceinline__ float sigm(float x) {
    return __builtin_amdgcn_rcpf(1.f + __expf(-x));
}
__device__ __forceinline__ float tanh_fast(float x) {
    return 2.f * sigm(2.f * x) - 1.f;
}

// In-lane LSTM cell update: acc regs = {i,f,g,o} for this lane's (unit,batch)
#define ACT_UPDATE(acc, c, hval)                                   \
    {                                                              \
        float gi = sigm((acc)[0]);                                 \
        float gf = sigm((acc)[1]);                                 \
        float gg = tanh_fast((acc)[2]);                            \
        float go = sigm((acc)[3]);                                 \
        (c) = gf * (c) + gi * gg;                                  \
        (hval) = go * tanh_fast((c));                              \
    }

__global__ __launch_bounds__(1024, 1) void lstm2_dense_kernel(
    const float* __restrict__ imu,
    const float* __restrict__ w_ih0, const float* __restrict__ w_hh0,
    const float* __restrict__ b_ih0, const float* __restrict__ b_hh0,
    const float* __restrict__ w_ih1, const float* __restrict__ w_hh1,
    const float* __restrict__ b_ih1, const float* __restrict__ b_hh1,
    const float* __restrict__ wf, const float* __restrict__ bf,
    const float* __restrict__ wn, const float* __restrict__ bn,
    float* __restrict__ out)
{
    const int tid   = threadIdx.x;
    const int l     = tid & 63;
    const int w     = tid >> 6;          // 16 waves
    const int layer = w >> 3;            // 0: LSTM1, 1: LSTM2
    const int tau   = w & 7;             // tile 0..7 (units 4tau..4tau+3)
    const int c     = l & 15;            // batch (all 16 valid!)
    const int q     = l >> 4;            // k-group / D row-quad
    const int unit  = 4 * tau + q;       // this lane's unit

    __shared__ __align__(16) short xfrag[TT + 4][BPB][8];  // [t][batch][k] bf16; +4 pad rows
    __shared__ __align__(16) short h1f[2][16][40];         // [parity][batch][unit] bf16
    __shared__ __align__(16) short h2f[2][16][40];
    __shared__ __align__(16) float lasth[16][36];          // [batch][unit] fp32

    // ---- zero h buffers and xfrag pad rows
    {
        short* p1 = &h1f[0][0][0];
        short* p2 = &h2f[0][0][0];
        for (int i = tid; i < 2 * 16 * 40; i += 1024) { p1[i] = 0; p2[i] = 0; }
        short* px = &xfrag[TT][0][0];
        if (tid < 4 * BPB * 8) px[tid] = 0;
    }

    // ---- stage x into [t][batch][k] bf16
    {
        const int bg0 = blockIdx.x * BPB;
        for (int p = tid; p < BPB * TT; p += 1024) {
            const int bb = p >> 9;           // 0..15
            const int t  = p & (TT - 1);
            const float* src = imu + ((size_t)(bg0 + bb) * TT + t) * 6;
            float2 a0 = *(const float2*)(src);
            float2 a1 = *(const float2*)(src + 2);
            float2 a2 = *(const float2*)(src + 4);
            unsigned* dst = (unsigned*)&xfrag[t][bb][0];
            dst[0] = (unsigned short)f2bf(a0.x) | ((unsigned)(unsigned short)f2bf(a0.y) << 16);
            dst[1] = (unsigned short)f2bf(a1.x) | ((unsigned)(unsigned short)f2bf(a1.y) << 16);
            dst[2] = (unsigned short)f2bf(a2.x) | ((unsigned)(unsigned short)f2bf(a2.y) << 16);
            dst[3] = 0u;
        }
    }

    // ---- A-fragments: rows = weight rows, unit-major gate order.
    // frag row m=c -> gate G = (m&3)*32 + 4*tau + (m>>2); D reg r = gate type r
    // for unit = 4*tau+q, batch c. Fully dense: one (unit,batch) per lane.
    const int G = (c & 3) * 32 + 4 * tau + (c >> 2);
    short8 AF, AS;                       // x-or-h1in operand, recurrent operand
    f32x4 bias;
    if (layer == 0) {
        #pragma unroll
        for (int j = 0; j < 8; ++j) {
            AF[j] = (q == 0 && j < 6) ? f2bf(w_ih0[G * 6 + j]) : (short)0;
            AS[j] = f2bf(w_hh0[G * 32 + q * 8 + j]);
        }
        #pragma unroll
        for (int r = 0; r < 4; ++r)
            bias[r] = b_ih0[r * 32 + unit] + b_hh0[r * 32 + unit];
    } else {
        #pragma unroll
        for (int j = 0; j < 8; ++j) {
            AF[j] = f2bf(w_ih1[G * 32 + q * 8 + j]);
            AS[j] = f2bf(w_hh1[G * 32 + q * 8 + j]);
        }
        #pragma unroll
        for (int r = 0; r < 4; ++r)
            bias[r] = b_ih1[r * 32 + unit] + b_hh1[r * 32 + unit];
    }

    float cst = 0.f;                     // this lane's cell state

    const short8* h1r0 = (const short8*)&h1f[0][c][q * 8];
    const short8* h1r1 = (const short8*)&h1f[1][c][q * 8];
    const short8* h2r0 = (const short8*)&h2f[0][c][q * 8];
    const short8* h2r1 = (const short8*)&h2f[1][c][q * 8];

    __syncthreads();

    // ======== prologue: L1 gates(0) with h1=0; prime xacc = x(1)-partial ========
    short8 xvE = (short8)0, xvO = (short8)0;
    f32x4 xacc = bias;
    if (layer == 0) {
        short8 xv = *(const short8*)&xfrag[0][c][0];
        f32x4 a = __builtin_amdgcn_mfma_f32_16x16x32_bf16(AF, xv, bias, 0, 0, 0);
        float h;
        ACT_UPDATE(a, cst, h);
        h1f[1][c][unit] = cvt_bf16(h);
        short8 xv1 = *(const short8*)&xfrag[1][c][0];
        xacc = __builtin_amdgcn_mfma_f32_16x16x32_bf16(AF, xv1, bias, 0, 0, 0);
        xvE = *(const short8*)&xfrag[2][c][0];
    }
    __syncthreads();

    // ======== main loop: STEP(T) = L1 gates(T+1) || L2 gates(T) ========
    // h written at parity T&1; read at parity (T+1)&1; 1 barrier/step.
#define STEP(T, H1R, H2R, WP, XVC, XVL)                                         \
    {                                                                           \
        if (layer == 0) {                                                       \
            short8 hv = *(H1R);                                                 \
            f32x4 a = __builtin_amdgcn_mfma_f32_16x16x32_bf16(AS, hv, xacc, 0, 0, 0); \
            float h;                                                            \
            ACT_UPDATE(a, cst, h);                                              \
            h1f[WP][c][unit] = cvt_bf16(h);                                     \
            xacc = __builtin_amdgcn_mfma_f32_16x16x32_bf16(AF, XVC, bias, 0, 0, 0); \
            XVL = *(const short8*)&xfrag[(T) + 3][c][0];                        \
        } else {                                                                \
            short8 av = *(H1R);                                                 \
            short8 bv = *(H2R);                                                 \
            f32x4 a = __builtin_amdgcn_mfma_f32_16x16x32_bf16(AF, av, bias, 0, 0, 0); \
            a = __builtin_amdgcn_mfma_f32_16x16x32_bf16(AS, bv, a, 0, 0, 0);    \
            float h;                                                            \
            ACT_UPDATE(a, cst, h);                                              \
            h2f[WP][c][unit] = cvt_bf16(h);                                     \
        }                                                                       \
        __syncthreads();                                                        \
    }

    #pragma unroll 1
    for (int t = 0; t < TT - 2; t += 2) {
        STEP(t,     h1r1, h2r1, 0, xvE, xvO)   // even T: read parity 1, write 0
        STEP(t + 1, h1r0, h2r0, 1, xvO, xvE)   // odd  T: read parity 0, write 1
    }
    STEP(TT - 2, h1r1, h2r1, 0, xvE, xvO)      // T=510 (prefetch hits pad rows)

    // ======== epilogue: L2 gates(511) -> lasth (fp32) ========
    if (layer == 1) {
        short8 av = *h1r0;           // h1(511) at parity 0
        short8 bv = *h2r0;           // h2(510) at parity 0
        f32x4 a = __builtin_amdgcn_mfma_f32_16x16x32_bf16(AF, av, bias, 0, 0, 0);
        a = __builtin_amdgcn_mfma_f32_16x16x32_bf16(AS, bv, a, 0, 0, 0);
        float h;
        ACT_UPDATE(a, cst, h);
        lasth[c][unit] = h;
    }
    __syncthreads();

    // ======== heads: 1024 threads = 16 batches x 64 outputs ========
    {
        const int bb = tid >> 6;           // 0..15 (wave-uniform)
        const int o  = tid & 63;
        float accF = bf[o], accN = bn[o];
        const float4* wf4 = (const float4*)(wf + o * 32);
        const float4* wn4 = (const float4*)(wn + o * 32);
        const float4* hv4 = (const float4*)&lasth[bb][0];
        #pragma unroll
        for (int k = 0; k < 8; ++k) {
            float4 h4 = hv4[k];
            float4 f4 = wf4[k];
            float4 n4 = wn4[k];
            accF += f4.x * h4.x + f4.y * h4.y + f4.z * h4.z + f4.w * h4.w;
            accN += n4.x * h4.x + n4.y * h4.y + n4.z * h4.z + n4.w * h4.w;
        }
        const size_t bg = (size_t)blockIdx.x * BPB + bb;
        out[bg * OUTD + o] = accF;
        out[(size_t)2048 * OUTD + bg * OUTD + o] = __expf(accN);
    }
}

extern "C" void kernel_launch(void* const* d_in, const int* in_sizes, int n_in,
                              void* d_out, int out_size, void* d_ws, size_t ws_size,
                              hipStream_t stream) {
    const float* imu   = (const float*)d_in[0];
    const float* w_ih0 = (const float*)d_in[1];
    const float* w_hh0 = (const float*)d_in[2];
    const float* b_ih0 = (const float*)d_in[3];
    const float* b_hh0 = (const float*)d_in[4];
    const float* w_ih1 = (const float*)d_in[5];
    const float* w_hh1 = (const float*)d_in[6];
    const float* b_ih1 = (const float*)d_in[7];
    const float* b_hh1 = (const float*)d_in[8];
    const float* wf    = (const float*)d_in[9];
    const float* bf    = (const float*)d_in[10];
    const float* wn    = (const float*)d_in[11];
    const float* bn    = (const float*)d_in[12];
    float* out = (float*)d_out;

    lstm2_dense_kernel<<<dim3(NBLK), dim3(1024), 0, stream>>>(
        imu, w_ih0, w_hh0, b_ih0, b_hh0,
        w_ih1, w_hh1, b_ih1, b_hh1,
        wf, bf, wn, bn, out);
}